// Round 4
// baseline (467.823 us; speedup 1.0000x reference)
//
#include <hip/hip_runtime.h>
#include <hip/hip_bf16.h>

// Fused windowed MHA (f32 I/O): LN -> QKV -> 12-head attention (+rel-pos bias LUT) -> out proj.
// prep_kernel: w_qkv/w_out f32->bf16 into d_ws, bias LUT gather (f32).
// fused kernel: one block per window (B=2048), 512 threads = 8 waves, 3 groups x 4 heads,
// all matmuls via v_mfma_f32_16x16x32_bf16 with f32 accumulation.

#define NTOK  64
#define CCH   384
#define NH    12
#define HD    32
#define EPSV  1e-5f
#define SCALEQ 0.17677669529663687f   // 1/sqrt(32)

#define WQKV_ELEMS (1152 * 384)
#define WOUT_ELEMS (384 * 384)
#define BLUT_ELEMS (NH * 64 * 64)

typedef __attribute__((ext_vector_type(8))) short  short8;   // 8 bf16 (A/B frag)
typedef __attribute__((ext_vector_type(4))) short  short4v;  // 4 bf16 (b64 write)
typedef __attribute__((ext_vector_type(4))) float  float4v;  // C/D frag / f32 loads

__device__ __forceinline__ unsigned short f2bf(float f) {
    union { float f; unsigned int i; } v; v.f = f;
    unsigned int r = v.i + 0x7fffu + ((v.i >> 16) & 1u);   // RNE
    return (unsigned short)(r >> 16);
}

__global__ void prep_kernel(const float* __restrict__ w_qkv_f,
                            const float* __restrict__ w_out_f,
                            const float* __restrict__ bias_tab,
                            const int*   __restrict__ rel_idx,
                            unsigned short* __restrict__ wq_bf,
                            unsigned short* __restrict__ wo_bf,
                            float* __restrict__ blut) {
    const int stride = gridDim.x * blockDim.x;
    const int tid = blockIdx.x * blockDim.x + threadIdx.x;
    for (int i = tid; i < WQKV_ELEMS; i += stride) wq_bf[i] = f2bf(w_qkv_f[i]);
    for (int i = tid; i < WOUT_ELEMS; i += stride) wo_bf[i] = f2bf(w_out_f[i]);
    for (int i = tid; i < BLUT_ELEMS; i += stride) {
        const int h = i >> 12, nm = i & 4095;              // blut[h][n][m]
        blut[i] = bias_tab[rel_idx[nm] * NH + h];
    }
}

__global__ __launch_bounds__(512, 2)
void fused_win_mha(const float* __restrict__ x,
                   const float* __restrict__ ln_g,
                   const float* __restrict__ ln_b,
                   const float* __restrict__ b_out,
                   const unsigned short* __restrict__ w_qkv,   // bf16 [1152][384]
                   const unsigned short* __restrict__ w_out,   // bf16 [384][384]
                   const float* __restrict__ blut,             // f32 [12][64][64]
                   float* __restrict__ out)                    // f32 [B][64][384]
{
    const int b    = blockIdx.x;
    const int t    = threadIdx.x;
    const int wav  = t >> 6;        // 0..7
    const int lane = t & 63;
    const int l4   = lane >> 4;     // 0..3
    const int lc   = lane & 15;     // 0..15
    const int lh   = wav >> 1;      // head-local 0..3 (attention phases)
    const int mh   = wav & 1;       // m-half (attention phases)

    __shared__ unsigned short xn[NTOK][CCH + 8];          // 50176 B
    __shared__ unsigned short qbuf[4][NTOK][HD + 8];      // 20480 B (att overlays q)
    __shared__ unsigned short kbuf[4][NTOK][HD + 8];      // 20480 B
    __shared__ unsigned short vT[4][HD][NTOK + 8];        // 18432 B (V transposed)
    __shared__ unsigned short pbuf[4][NTOK][NTOK + 8];    // 36864 B
    // total 146432 B -> 1 block/CU

    // ---------------- LayerNorm (f32 x -> bf16 xn) ----------------
    {
        const int row = t >> 3, seg = t & 7;              // 8 threads per token row
        const float* xr = x + (b * NTOK + row) * CCH + seg * 48;
        float vals[48];
        float s = 0.f, s2 = 0.f;
        #pragma unroll
        for (int i = 0; i < 12; ++i) {
            float4v v = *(const float4v*)(xr + i * 4);
            #pragma unroll
            for (int j = 0; j < 4; ++j) {
                float f = v[j];
                vals[i * 4 + j] = f; s += f; s2 += f * f;
            }
        }
        s += __shfl_xor(s, 1); s2 += __shfl_xor(s2, 1);
        s += __shfl_xor(s, 2); s2 += __shfl_xor(s2, 2);
        s += __shfl_xor(s, 4); s2 += __shfl_xor(s2, 4);
        const float mu   = s * (1.f / CCH);
        const float rstd = rsqrtf(s2 * (1.f / CCH) - mu * mu + EPSV);
        #pragma unroll
        for (int i = 0; i < 12; ++i) {
            float4v gv = *(const float4v*)(ln_g + seg * 48 + i * 4);
            float4v bv = *(const float4v*)(ln_b + seg * 48 + i * 4);
            #pragma unroll
            for (int j = 0; j < 4; ++j)
                xn[row][seg * 48 + i * 4 + j] = f2bf((vals[i * 4 + j] - mu) * rstd * gv[j] + bv[j]);
        }
    }
    __syncthreads();

    // persistent GEMM2 accumulators: [mt 0..3][j2 0..2] -> C cols 16*(3*wav+j2)+lc
    float4v facc[4][3];
    #pragma unroll
    for (int mt = 0; mt < 4; ++mt)
        #pragma unroll
        for (int j = 0; j < 3; ++j)
            facc[mt][j] = (float4v){0.f, 0.f, 0.f, 0.f};

    for (int grp = 0; grp < 3; ++grp) {
        const int h = 4 * grp + lh;   // global head for this wave's attention work

        // ---------------- GEMM1: qkv chunk for heads 4g..4g+3 ----------------
        float4v acc[3][4];
        #pragma unroll
        for (int n = 0; n < 3; ++n)
            #pragma unroll
            for (int m = 0; m < 4; ++m)
                acc[n][m] = (float4v){0.f, 0.f, 0.f, 0.f};

        int eIdx[3];
        #pragma unroll
        for (int ntl = 0; ntl < 3; ++ntl) {
            const int part = 3 * mh + ntl;                 // 0,1:q 2,3:k 4,5:v halves
            eIdx[ntl] = (part >> 1) * CCH + h * HD + (part & 1) * 16 + lc;
        }
        for (int kk = 0; kk < 12; ++kk) {
            short8 aF[4];
            #pragma unroll
            for (int mt = 0; mt < 4; ++mt)
                aF[mt] = *(const short8*)&xn[16 * mt + lc][32 * kk + 8 * l4];
            #pragma unroll
            for (int ntl = 0; ntl < 3; ++ntl) {
                short8 bF = *(const short8*)(w_qkv + eIdx[ntl] * CCH + 32 * kk + 8 * l4);
                #pragma unroll
                for (int mt = 0; mt < 4; ++mt)
                    acc[ntl][mt] = __builtin_amdgcn_mfma_f32_16x16x32_bf16(aF[mt], bF, acc[ntl][mt], 0, 0, 0);
            }
        }
        __syncthreads();   // previous group's GEMM2 finished reading qbuf(att)

        // ---------------- scatter q(scaled),k,vT to LDS ----------------
        #pragma unroll
        for (int ntl = 0; ntl < 3; ++ntl) {
            const int part = 3 * mh + ntl;
            const int mat = part >> 1, half = part & 1;
            #pragma unroll
            for (int mt = 0; mt < 4; ++mt) {
                if (mat == 0) {
                    #pragma unroll
                    for (int r = 0; r < 4; ++r)
                        qbuf[lh][16 * mt + 4 * l4 + r][half * 16 + lc] = f2bf(acc[ntl][mt][r] * SCALEQ);
                } else if (mat == 1) {
                    #pragma unroll
                    for (int r = 0; r < 4; ++r)
                        kbuf[lh][16 * mt + 4 * l4 + r][half * 16 + lc] = f2bf(acc[ntl][mt][r]);
                } else {
                    short4v pk;
                    #pragma unroll
                    for (int r = 0; r < 4; ++r)
                        pk[r] = (short)f2bf(acc[ntl][mt][r]);
                    *(short4v*)&vT[lh][half * 16 + lc][16 * mt + 4 * l4] = pk;  // ds_write_b64
                }
            }
        }
        __syncthreads();   // qkv visible

        // ---------------- scores + bias + softmax (head h, rows 32*mh..32*mh+31) ----------------
        float sv[2][4][4];   // [j m-tile][kt key-tile][reg]
        {
            short8 qf[2];
            #pragma unroll
            for (int j = 0; j < 2; ++j)
                qf[j] = *(const short8*)&qbuf[lh][16 * (2 * mh + j) + lc][8 * l4];
            #pragma unroll
            for (int kt = 0; kt < 4; ++kt) {
                short8 kf = *(const short8*)&kbuf[lh][16 * kt + lc][8 * l4];
                #pragma unroll
                for (int j = 0; j < 2; ++j) {
                    float4v sres = __builtin_amdgcn_mfma_f32_16x16x32_bf16(
                        qf[j], kf, (float4v){0.f, 0.f, 0.f, 0.f}, 0, 0, 0);
                    #pragma unroll
                    for (int r = 0; r < 4; ++r) sv[j][kt][r] = sres[r];
                }
            }
        }
        const float* bl = blut + h * 4096;
        float rsum[2][4];
        #pragma unroll
        for (int j = 0; j < 2; ++j) {
            #pragma unroll
            for (int reg = 0; reg < 4; ++reg) {
                const int row = 16 * (2 * mh + j) + 4 * l4 + reg;
                const float* blr = bl + row * 64 + lc;
                float m = -1e30f;
                #pragma unroll
                for (int kt = 0; kt < 4; ++kt) {
                    sv[j][kt][reg] += blr[16 * kt];
                    m = fmaxf(m, sv[j][kt][reg]);
                }
                m = fmaxf(m, __shfl_xor(m, 1));
                m = fmaxf(m, __shfl_xor(m, 2));
                m = fmaxf(m, __shfl_xor(m, 4));
                m = fmaxf(m, __shfl_xor(m, 8));
                float s = 0.f;
                #pragma unroll
                for (int kt = 0; kt < 4; ++kt) {
                    float p = __expf(sv[j][kt][reg] - m);
                    sv[j][kt][reg] = p; s += p;
                }
                s += __shfl_xor(s, 1);
                s += __shfl_xor(s, 2);
                s += __shfl_xor(s, 4);
                s += __shfl_xor(s, 8);
                rsum[j][reg] = 1.f / s;
                #pragma unroll
                for (int kt = 0; kt < 4; ++kt)
                    pbuf[lh][row][16 * kt + lc] = f2bf(sv[j][kt][reg]);   // unnormalized
            }
        }
        __syncthreads();   // pbuf visible; all q reads complete (q now dead)

        // ---------------- PV ----------------
        float4v o[2][2];
        #pragma unroll
        for (int j = 0; j < 2; ++j)
            #pragma unroll
            for (int nt = 0; nt < 2; ++nt)
                o[j][nt] = (float4v){0.f, 0.f, 0.f, 0.f};
        #pragma unroll
        for (int kk2 = 0; kk2 < 2; ++kk2) {
            short8 pf[2], vf[2];
            #pragma unroll
            for (int j = 0; j < 2; ++j)
                pf[j] = *(const short8*)&pbuf[lh][16 * (2 * mh + j) + lc][32 * kk2 + 8 * l4];
            #pragma unroll
            for (int nt = 0; nt < 2; ++nt)
                vf[nt] = *(const short8*)&vT[lh][16 * nt + lc][32 * kk2 + 8 * l4];
            #pragma unroll
            for (int j = 0; j < 2; ++j)
                #pragma unroll
                for (int nt = 0; nt < 2; ++nt)
                    o[j][nt] = __builtin_amdgcn_mfma_f32_16x16x32_bf16(pf[j], vf[nt], o[j][nt], 0, 0, 0);
        }
        // normalize rows and write att into qbuf (q dead after p-barrier)
        #pragma unroll
        for (int j = 0; j < 2; ++j)
            #pragma unroll
            for (int nt = 0; nt < 2; ++nt)
                #pragma unroll
                for (int r = 0; r < 4; ++r)
                    qbuf[lh][16 * (2 * mh + j) + 4 * l4 + r][16 * nt + lc] =
                        f2bf(o[j][nt][r] * rsum[j][r]);
        __syncthreads();   // att visible

        // ---------------- GEMM2 partial: facc += att @ w_out[:, 128g..128g+127]^T ----------------
        #pragma unroll
        for (int ks = 0; ks < 4; ++ks) {       // ks = head-local index of att chunk
            short8 aG[4];
            #pragma unroll
            for (int mt = 0; mt < 4; ++mt)
                aG[mt] = *(const short8*)&qbuf[ks][16 * mt + lc][8 * l4];
            #pragma unroll
            for (int j2 = 0; j2 < 3; ++j2) {
                const int c = 16 * (3 * wav + j2) + lc;
                short8 bG = *(const short8*)(w_out + c * CCH + 128 * grp + 32 * ks + 8 * l4);
                #pragma unroll
                for (int mt = 0; mt < 4; ++mt)
                    facc[mt][j2] = __builtin_amdgcn_mfma_f32_16x16x32_bf16(aG[mt], bG, facc[mt][j2], 0, 0, 0);
            }
        }
        // no barrier needed here: next iteration's scatter is preceded by one
    }

    // ---------------- epilogue: facc + b_out -> direct f32 global stores ----------------
    {
        float* ob = out + b * (NTOK * CCH);
        #pragma unroll
        for (int mt = 0; mt < 4; ++mt) {
            #pragma unroll
            for (int j2 = 0; j2 < 3; ++j2) {
                const int c = 16 * (3 * wav + j2) + lc;
                const float bo = b_out[c];
                #pragma unroll
                for (int r = 0; r < 4; ++r)
                    ob[(16 * mt + 4 * l4 + r) * CCH + c] = facc[mt][j2][r] + bo;
            }
        }
    }
}

extern "C" void kernel_launch(void* const* d_in, const int* in_sizes, int n_in,
                              void* d_out, int out_size, void* d_ws, size_t ws_size,
                              hipStream_t stream) {
    const float* x     = (const float*)d_in[0];
    const float* ln_g  = (const float*)d_in[1];
    const float* ln_b  = (const float*)d_in[2];
    const float* w_qkv = (const float*)d_in[3];
    const float* w_out = (const float*)d_in[4];
    const float* b_out = (const float*)d_in[5];
    const float* btab  = (const float*)d_in[6];
    const int*   ridx  = (const int*)d_in[7];
    float*       out   = (float*)d_out;

    unsigned short* wq_bf = (unsigned short*)d_ws;
    unsigned short* wo_bf = wq_bf + WQKV_ELEMS;
    float*          blut  = (float*)(wo_bf + WOUT_ELEMS);   // byte offset 1179648, 16B-aligned

    prep_kernel<<<512, 256, 0, stream>>>(w_qkv, w_out, btab, ridx, wq_bf, wo_bf, blut);
    fused_win_mha<<<2048, 512, 0, stream>>>(x, ln_g, ln_b, b_out, wq_bf, wo_bf, blut, out);
}